// Round 1
// baseline (695.271 us; speedup 1.0000x reference)
//
#include <hip/hip_runtime.h>
#include <hip/hip_bf16.h>
#include <math.h>

// Problem constants (fixed by the reference)
#define DIM      1024
#define NH       16
#define DH       64
#define NSEQ     1605
#define HWIN     1600
#define PREFIX   (NSEQ - HWIN)   // 5
#define SCALE    0.125f          // 1/sqrt(64)
#define NEG_INF  (-1e30f)

// ---------------------------------------------------------------------------
// GEMM 1: qkv = x @ W_qkv^T, epilogue scatters into head-major Q/K/V buffers.
// C[n,m] = dot(x[n,:], W[m,:]); M=1605, N=3072, K=1024.
// Tile 64x64, BK=16, 256 threads, 4x4 microtile.
// ---------------------------------------------------------------------------
#define BM 64
#define BN 64
#define BK 16
#define LPAD 68   // LDS row stride (floats): 16B-aligned, <=2-way bank alias

__global__ __launch_bounds__(256) void gemm_qkv(
    const float* __restrict__ A, const float* __restrict__ B,
    float* __restrict__ Qh, float* __restrict__ Kh, float* __restrict__ Vh,
    int M, int K)
{
    __shared__ float As[BK][LPAD];
    __shared__ float Bs[BK][LPAD];
    const int tid = threadIdx.x;
    const int m0 = blockIdx.y * BM;
    const int n0 = blockIdx.x * BN;
    const int ty = tid >> 4, tx = tid & 15;
    const int lrow = tid >> 2;          // 0..63
    const int lk4  = (tid & 3) * 4;     // 0,4,8,12

    float acc[4][4] = {};

    for (int k0 = 0; k0 < K; k0 += BK) {
        {   // stage A tile (guard M)
            int gm = m0 + lrow;
            float4 v = {0.f, 0.f, 0.f, 0.f};
            if (gm < M) v = *(const float4*)&A[(size_t)gm * K + k0 + lk4];
            As[lk4 + 0][lrow] = v.x; As[lk4 + 1][lrow] = v.y;
            As[lk4 + 2][lrow] = v.z; As[lk4 + 3][lrow] = v.w;
        }
        {   // stage B tile (N=3072 divisible by 64, no guard)
            int gn = n0 + lrow;
            float4 v = *(const float4*)&B[(size_t)gn * K + k0 + lk4];
            Bs[lk4 + 0][lrow] = v.x; Bs[lk4 + 1][lrow] = v.y;
            Bs[lk4 + 2][lrow] = v.z; Bs[lk4 + 3][lrow] = v.w;
        }
        __syncthreads();
#pragma unroll
        for (int k = 0; k < BK; k++) {
            float4 a = *(const float4*)&As[k][ty * 4];
            float4 b = *(const float4*)&Bs[k][tx * 4];
            float av[4] = {a.x, a.y, a.z, a.w};
            float bv[4] = {b.x, b.y, b.z, b.w};
#pragma unroll
            for (int i = 0; i < 4; i++)
#pragma unroll
                for (int j = 0; j < 4; j++)
                    acc[i][j] += av[i] * bv[j];
        }
        __syncthreads();
    }

    // epilogue: whole 64-wide column tile shares (which, head)
    const int which = n0 / DIM;            // 0=Q 1=K 2=V
    const int h = (n0 % DIM) / DH;
    float* buf = (which == 0) ? Qh : (which == 1) ? Kh : Vh;
#pragma unroll
    for (int i = 0; i < 4; i++) {
        int gm = m0 + ty * 4 + i;
        if (gm < M) {
#pragma unroll
            for (int j = 0; j < 4; j++) {
                int d = tx * 4 + j;        // n0 % 64 == 0
                buf[((size_t)h * NSEQ + gm) * DH + d] = acc[i][j];
            }
        }
    }
}

// ---------------------------------------------------------------------------
// RoPE in place on Q and K, rows PREFIX..NSEQ-1. rope = [sin(1600,64); cos].
// ---------------------------------------------------------------------------
__global__ __launch_bounds__(64) void rope_kernel(
    float* __restrict__ Qh, float* __restrict__ Kh, const float* __restrict__ rope)
{
    const int r = blockIdx.x;       // 0..HWIN-1
    const int h = blockIdx.y;       // 0..NH-1
    const int which = blockIdx.z;   // 0=Q 1=K
    const int d = threadIdx.x;      // 0..63
    float* t = (which == 0 ? Qh : Kh) + ((size_t)h * NSEQ + (PREFIX + r)) * DH;
    float v = t[d];
    float partner = t[d ^ 32];
    float rot = (d < 32) ? -partner : partner;
    float s = rope[(size_t)r * DH + d];
    float c = rope[(size_t)HWIN * DH + (size_t)r * DH + d];
    float o = v * c + rot * s;
    __syncthreads();
    t[d] = o;
}

// ---------------------------------------------------------------------------
// Streaming (flash-style) attention. One block = (head, 32-query tile).
// 256 threads: thread t owns query row r=t>>3 and dims dg=(t&7)*8 .. +8.
// Keys streamed in 64-wide tiles; online softmax with 8-lane shfl reductions.
// ---------------------------------------------------------------------------
#define BQ   32
#define BKEY 64

__global__ __launch_bounds__(256) void attn_kernel(
    const float* __restrict__ Qh, const float* __restrict__ Kh,
    const float* __restrict__ Vh, float* __restrict__ O)
{
    __shared__ float qs[BQ][LPAD];
    __shared__ float ks[BKEY][LPAD];
    __shared__ float vs[BKEY][LPAD];
    __shared__ float ss[BQ][LPAD];
    __shared__ float mrow[BQ], lrow[BQ];

    const int h  = blockIdx.y;
    const int q0 = blockIdx.x * BQ;
    const int tid = threadIdx.x;
    const int r   = tid >> 3;          // owned query row 0..31
    const int c0p = tid & 7;           // score column base (interleaved by 8)
    const int dg  = (tid & 7) * 8;     // owned dim group

    // stage Q tile, pre-scaled
    for (int i = tid; i < BQ * DH / 4; i += 256) {
        int rr = i >> 4;               // DH/4 = 16 float4 per row
        int c4 = (i & 15) * 4;
        int q = q0 + rr;
        float4 v = {0.f, 0.f, 0.f, 0.f};
        if (q < NSEQ) v = *(const float4*)&Qh[((size_t)h * NSEQ + q) * DH + c4];
        v.x *= SCALE; v.y *= SCALE; v.z *= SCALE; v.w *= SCALE;
        *(float4*)&qs[rr][c4] = v;
    }
    if (tid < BQ) { mrow[tid] = NEG_INF; lrow[tid] = 0.f; }
    float acc[8] = {};
    __syncthreads();

    for (int j0 = 0; j0 < NSEQ; j0 += BKEY) {
        // stage K/V tiles
        for (int i = tid; i < BKEY * DH / 4; i += 256) {
            int kr = i >> 4;
            int c4 = (i & 15) * 4;
            int j = j0 + kr;
            float4 kv = {0.f, 0.f, 0.f, 0.f}, vv = {0.f, 0.f, 0.f, 0.f};
            if (j < NSEQ) {
                kv = *(const float4*)&Kh[((size_t)h * NSEQ + j) * DH + c4];
                vv = *(const float4*)&Vh[((size_t)h * NSEQ + j) * DH + c4];
            }
            *(float4*)&ks[kr][c4] = kv;
            *(float4*)&vs[kr][c4] = vv;
        }
        __syncthreads();

        // scores: thread computes cols c = c0p + 8*j (interleaved -> no bank conflicts)
        float s[8] = {};
        for (int k4 = 0; k4 < DH; k4 += 4) {
            float4 a = *(const float4*)&qs[r][k4];
#pragma unroll
            for (int j = 0; j < 8; j++) {
                float4 b = *(const float4*)&ks[c0p + 8 * j][k4];
                s[j] += a.x * b.x + a.y * b.y + a.z * b.z + a.w * b.w;
            }
        }
#pragma unroll
        for (int j = 0; j < 8; j++)
            if (j0 + c0p + 8 * j >= NSEQ) s[j] = NEG_INF;

        // online softmax: 8-lane reductions (lanes of a row group are consecutive)
        float tmax = s[0];
#pragma unroll
        for (int j = 1; j < 8; j++) tmax = fmaxf(tmax, s[j]);
        for (int off = 1; off < 8; off <<= 1)
            tmax = fmaxf(tmax, __shfl_xor(tmax, off));

        float m_old = mrow[r];
        float m_new = fmaxf(m_old, tmax);
        float scale_old = __expf(m_old - m_new);

        float psum = 0.f;
#pragma unroll
        for (int j = 0; j < 8; j++) {
            float p = __expf(s[j] - m_new);
            ss[r][c0p + 8 * j] = p;
            psum += p;
        }
        for (int off = 1; off < 8; off <<= 1)
            psum += __shfl_xor(psum, off);

        if (c0p == 0) {
            mrow[r] = m_new;
            lrow[r] = lrow[r] * scale_old + psum;
        }
        __syncthreads();   // safety: make full prob row visible before PV

        // PV: acc[d] = acc[d]*scale_old + sum_j p[j] * V[j][d]
#pragma unroll
        for (int i = 0; i < 8; i++) acc[i] *= scale_old;
#pragma unroll 8
        for (int j = 0; j < BKEY; j++) {
            float p = ss[r][j];
            float4 v0 = *(const float4*)&vs[j][dg];
            float4 v1 = *(const float4*)&vs[j][dg + 4];
            acc[0] += p * v0.x; acc[1] += p * v0.y;
            acc[2] += p * v0.z; acc[3] += p * v0.w;
            acc[4] += p * v1.x; acc[5] += p * v1.y;
            acc[6] += p * v1.z; acc[7] += p * v1.w;
        }
        __syncthreads();   // protect ks/vs/ss/mrow/lrow for next tile
    }

    // epilogue: O[q][h*64 + d] = acc/l  (row-major for the proj GEMM)
    const int q = q0 + r;
    if (q < NSEQ) {
        float inv = 1.0f / lrow[r];
        float4 o0 = {acc[0] * inv, acc[1] * inv, acc[2] * inv, acc[3] * inv};
        float4 o1 = {acc[4] * inv, acc[5] * inv, acc[6] * inv, acc[7] * inv};
        *(float4*)&O[(size_t)q * DIM + h * DH + dg]     = o0;
        *(float4*)&O[(size_t)q * DIM + h * DH + dg + 4] = o1;
    }
}

// ---------------------------------------------------------------------------
// GEMM 2: out = O @ W_proj^T + b_proj. M=1605, N=1024, K=1024.
// ---------------------------------------------------------------------------
__global__ __launch_bounds__(256) void gemm_proj(
    const float* __restrict__ A, const float* __restrict__ B,
    const float* __restrict__ bias, float* __restrict__ C,
    int M, int K)
{
    __shared__ float As[BK][LPAD];
    __shared__ float Bs[BK][LPAD];
    const int tid = threadIdx.x;
    const int m0 = blockIdx.y * BM;
    const int n0 = blockIdx.x * BN;
    const int ty = tid >> 4, tx = tid & 15;
    const int lrow = tid >> 2;
    const int lk4  = (tid & 3) * 4;

    float acc[4][4] = {};

    for (int k0 = 0; k0 < K; k0 += BK) {
        {
            int gm = m0 + lrow;
            float4 v = {0.f, 0.f, 0.f, 0.f};
            if (gm < M) v = *(const float4*)&A[(size_t)gm * K + k0 + lk4];
            As[lk4 + 0][lrow] = v.x; As[lk4 + 1][lrow] = v.y;
            As[lk4 + 2][lrow] = v.z; As[lk4 + 3][lrow] = v.w;
        }
        {
            int gn = n0 + lrow;
            float4 v = *(const float4*)&B[(size_t)gn * K + k0 + lk4];
            Bs[lk4 + 0][lrow] = v.x; Bs[lk4 + 1][lrow] = v.y;
            Bs[lk4 + 2][lrow] = v.z; Bs[lk4 + 3][lrow] = v.w;
        }
        __syncthreads();
#pragma unroll
        for (int k = 0; k < BK; k++) {
            float4 a = *(const float4*)&As[k][ty * 4];
            float4 b = *(const float4*)&Bs[k][tx * 4];
            float av[4] = {a.x, a.y, a.z, a.w};
            float bv[4] = {b.x, b.y, b.z, b.w};
#pragma unroll
            for (int i = 0; i < 4; i++)
#pragma unroll
                for (int j = 0; j < 4; j++)
                    acc[i][j] += av[i] * bv[j];
        }
        __syncthreads();
    }

#pragma unroll
    for (int i = 0; i < 4; i++) {
        int gm = m0 + ty * 4 + i;
        if (gm < M) {
#pragma unroll
            for (int j = 0; j < 4; j++) {
                int gn = n0 + tx * 4 + j;
                C[(size_t)gm * DIM + gn] = acc[i][j] + bias[gn];
            }
        }
    }
}

// ---------------------------------------------------------------------------
extern "C" void kernel_launch(void* const* d_in, const int* in_sizes, int n_in,
                              void* d_out, int out_size, void* d_ws, size_t ws_size,
                              hipStream_t stream)
{
    const float* x     = (const float*)d_in[0];
    const float* rope  = (const float*)d_in[1];
    const float* Wqkv  = (const float*)d_in[2];
    const float* Wproj = (const float*)d_in[3];
    const float* bproj = (const float*)d_in[4];
    float* out = (float*)d_out;

    float* ws = (float*)d_ws;
    const size_t HS = (size_t)NH * NSEQ * DH;   // 1,643,520 floats per tensor
    float* Qh = ws;
    float* Kh = ws + HS;
    float* Vh = ws + 2 * HS;
    float* O  = ws + 3 * HS;

    // 1) QKV GEMM + head-major scatter
    gemm_qkv<<<dim3(3 * DIM / BN, (NSEQ + BM - 1) / BM), 256, 0, stream>>>(
        x, Wqkv, Qh, Kh, Vh, NSEQ, DIM);

    // 2) RoPE in place on Q and K
    rope_kernel<<<dim3(HWIN, NH, 2), 64, 0, stream>>>(Qh, Kh, rope);

    // 3) streaming attention -> O (row-major [seq][DIM])
    attn_kernel<<<dim3((NSEQ + BQ - 1) / BQ, NH), 256, 0, stream>>>(Qh, Kh, Vh, O);

    // 4) output projection + bias
    gemm_proj<<<dim3(DIM / BN, (NSEQ + BM - 1) / BM), 256, 0, stream>>>(
        O, Wproj, bproj, out, NSEQ, DIM);
}